// Round 3
// baseline (551.046 us; speedup 1.0000x reference)
//
#include <hip/hip_runtime.h>

#define Nn 8192
#define Ee 262144
#define NEGk 4

// ---- workspace float offsets ----
#define OFF_H1   0u
#define OFF_M1   524288u
#define OFF_V1   1048576u
#define OFF_NN   1572864u
#define OFF_H2   2097152u
#define OFF_V2   2621440u
#define OFF_NV   3145728u
#define OFF_M2   3670016u
#define OFF_SC   4194304u
#define OFF_CNT  4203008u
#define OFF_CUR  4211200u
#define OFF_RS   4219392u
#define OFF_ESRC 4227600u
#define OFF_EW   4489744u
#define OFF_EAW  4751888u
#define OFF_NVH  5014032u   // 8192*64 ushort = 262144 floats
#define OFF_NVL  5276176u
#define OFF_WT   5538320u   // 5 * 4096 floats of transposed weights

using short8 = __attribute__((ext_vector_type(8))) short;
using f32x4  = __attribute__((ext_vector_type(4))) float;

__device__ inline float wave_sum(float v){
  #pragma unroll
  for (int o = 32; o > 0; o >>= 1) v += __shfl_down(v, o, 64);
  return v;
}
__device__ inline float wave_max(float v){
  #pragma unroll
  for (int o = 32; o > 0; o >>= 1) v = fmaxf(v, __shfl_down(v, o, 64));
  return v;
}
__device__ inline unsigned short f2bf(float x){
  unsigned u = __float_as_uint(x);
  unsigned r = (u + 0x7FFFu + ((u >> 16) & 1u)) >> 16;
  return (unsigned short)r;
}
__device__ inline float bf2f(unsigned short h){ return __uint_as_float(((unsigned)h) << 16); }

// ---------------- prep: weight transposes + zero cnt/cur + zero out[0:4] ----------------
__global__ __launch_bounds__(256) void prep_k(const float* __restrict__ W1, const float* __restrict__ B1,
    const float* __restrict__ W2, const float* __restrict__ Wq, const float* __restrict__ B2,
    float* __restrict__ Wt, int* __restrict__ cnt, int* __restrict__ cur, float* __restrict__ out4){
  int idx = blockIdx.x * 256 + threadIdx.x;
  if (idx < 20480){
    int m = idx >> 12, rc = idx & 4095;
    int k = rc >> 6, c = rc & 63;
    const float* src = (m == 0) ? W1 : (m == 1) ? B1 : (m == 2) ? W2 : (m == 3) ? Wq : B2;
    Wt[m * 4096 + c * 64 + k] = src[k * 64 + c];
  } else if (idx < 28672){
    cnt[idx - 20480] = 0;
  } else if (idx < 36864){
    cur[idx - 28672] = 0;
  } else if (idx < 36868){
    out4[idx - 36864] = 0.f;
  }
}

// ---------------- CSR build ----------------
__global__ __launch_bounds__(256) void hist_k(const int* __restrict__ dst, int* __restrict__ cnt){
  int e = blockIdx.x * 256 + threadIdx.x;
  atomicAdd(&cnt[dst[e]], 1);
}

__global__ __launch_bounds__(256) void scan_k(const int* __restrict__ cnt, int* __restrict__ rs){
  __shared__ int part[256];
  int tid = threadIdx.x;
  int base = tid * 32;
  int local[32]; int s = 0;
  #pragma unroll
  for (int i = 0; i < 32; i++){ local[i] = s; s += cnt[base + i]; }
  part[tid] = s; __syncthreads();
  for (int off = 1; off < 256; off <<= 1){
    int v = (tid >= off) ? part[tid - off] : 0;
    __syncthreads();
    part[tid] += v;
    __syncthreads();
  }
  int ex = part[tid] - s;
  #pragma unroll
  for (int i = 0; i < 32; i++) rs[base + i] = ex + local[i];
  if (tid == 255) rs[Nn] = part[255];
}

__global__ __launch_bounds__(256) void scatter_k(const int* __restrict__ dst, const int* __restrict__ src,
    const float* __restrict__ ew, const float* __restrict__ aw,
    const int* __restrict__ rs, int* __restrict__ cur,
    int* __restrict__ cs, float* __restrict__ cw, float* __restrict__ caw){
  int e = blockIdx.x * 256 + threadIdx.x;
  int d = dst[e];
  int pos = atomicAdd(&cur[d], 1);
  int j = rs[d] + pos;
  cs[j] = src[e]; cw[j] = ew[e]; caw[j] = aw[e];
}

// ---------------- FC: Y = X(Nx64) @ W(64x64), W pre-transposed; optional dual ----------------
template<bool DUAL>
__global__ __launch_bounds__(256) void fc2_k(const float* __restrict__ X,
    const float* __restrict__ WtA, const float* __restrict__ WtB,
    float* __restrict__ Ya, float* __restrict__ Yb){
  __shared__ float As[32 * 68];
  int tid = threadIdx.x;
  int r0 = blockIdx.x * 32;
  for (int i = tid; i < 512; i += 256){
    int r = i >> 4, kq = (i & 15) << 2;
    *(float4*)(As + r * 68 + kq) = *(const float4*)(X + (r0 + r) * 64 + kq);
  }
  __syncthreads();
  int tx = tid & 63, wv = tid >> 6;
  float acca[8], accb[8];
  #pragma unroll
  for (int r = 0; r < 8; r++){ acca[r] = 0.f; accb[r] = 0.f; }
  const float* wpa = WtA + tx * 64;
  const float* wpb = DUAL ? (WtB + tx * 64) : WtA;
  #pragma unroll 4
  for (int kq = 0; kq < 64; kq += 4){
    float4 w = *(const float4*)(wpa + kq);
    float4 w2 = *(const float4*)(wpb + kq);
    #pragma unroll
    for (int r = 0; r < 8; r++){
      float4 a = *(const float4*)(As + (wv * 8 + r) * 68 + kq);
      acca[r] += a.x * w.x + a.y * w.y + a.z * w.z + a.w * w.w;
      if (DUAL) accb[r] += a.x * w2.x + a.y * w2.y + a.z * w2.z + a.w * w2.w;
    }
  }
  #pragma unroll
  for (int r = 0; r < 8; r++){
    int row = r0 + wv * 8 + r;
    Ya[row * 64 + tx] = acca[r];
    if (DUAL) Yb[row * 64 + tx] = accb[r];
  }
}

// ---------------- fused: nv = prelu(v2@Wq + bq); bf16-split(nv); M2 = nv@B2 ----------------
__global__ __launch_bounds__(256) void fcq_k(const float* __restrict__ X,
    const float* __restrict__ Wtq, const float* __restrict__ WtB2,
    const float* __restrict__ bias, const float* __restrict__ alpha,
    float* __restrict__ nv, float* __restrict__ M2,
    unsigned short* __restrict__ hi, unsigned short* __restrict__ lo){
  __shared__ float As[32 * 68];
  __shared__ float Ns[32 * 68];
  int tid = threadIdx.x;
  int r0 = blockIdx.x * 32;
  for (int i = tid; i < 512; i += 256){
    int r = i >> 4, kq = (i & 15) << 2;
    *(float4*)(As + r * 68 + kq) = *(const float4*)(X + (r0 + r) * 64 + kq);
  }
  __syncthreads();
  int tx = tid & 63, wv = tid >> 6;
  float acc[8];
  #pragma unroll
  for (int r = 0; r < 8; r++) acc[r] = 0.f;
  const float* wp = Wtq + tx * 64;
  #pragma unroll 4
  for (int kq = 0; kq < 64; kq += 4){
    float4 w = *(const float4*)(wp + kq);
    #pragma unroll
    for (int r = 0; r < 8; r++){
      float4 a = *(const float4*)(As + (wv * 8 + r) * 68 + kq);
      acc[r] += a.x * w.x + a.y * w.y + a.z * w.z + a.w * w.w;
    }
  }
  float al = alpha[0];
  float bi = bias[tx];
  #pragma unroll
  for (int r = 0; r < 8; r++){
    int row = r0 + wv * 8 + r;
    float x = acc[r] + bi;
    x = (x >= 0.f) ? x : al * x;
    nv[row * 64 + tx] = x;
    unsigned short h = f2bf(x);
    hi[row * 64 + tx] = h;
    lo[row * 64 + tx] = f2bf(x - bf2f(h));
    Ns[(wv * 8 + r) * 68 + tx] = x;
  }
  __syncthreads();
  // second matmul: M2 = Ns @ B2 (B2 pre-transposed)
  float acc2[8];
  #pragma unroll
  for (int r = 0; r < 8; r++) acc2[r] = 0.f;
  const float* wp2 = WtB2 + tx * 64;
  #pragma unroll 4
  for (int kq = 0; kq < 64; kq += 4){
    float4 w = *(const float4*)(wp2 + kq);
    #pragma unroll
    for (int r = 0; r < 8; r++){
      float4 a = *(const float4*)(Ns + (wv * 8 + r) * 68 + kq);
      acc2[r] += a.x * w.x + a.y * w.y + a.z * w.z + a.w * w.w;
    }
  }
  #pragma unroll
  for (int r = 0; r < 8; r++){
    int row = r0 + wv * 8 + r;
    M2[row * 64 + tx] = acc2[r];
  }
}

// ---------------- SpMM aggregation (CSR), 4x unrolled ----------------
template<bool DUAL>
__global__ __launch_bounds__(256) void agg_k(const float* __restrict__ h,
    const int* __restrict__ rs, const int* __restrict__ cs,
    const float* __restrict__ cw, const float* __restrict__ caw,
    const float* __restrict__ bias, const float* __restrict__ alpha,
    float* __restrict__ out1, float* __restrict__ out2){
  int node = (blockIdx.x << 2) + (threadIdx.x >> 6);
  int lane = threadIdx.x & 63;
  int s = rs[node], e = rs[node + 1];
  float acc = 0.f, acc2 = 0.f;
  int i = s;
  for (; i + 4 <= e; i += 4){
    int s0 = cs[i], s1 = cs[i+1], s2 = cs[i+2], s3 = cs[i+3];
    float w0 = cw[i], w1 = cw[i+1], w2 = cw[i+2], w3 = cw[i+3];
    float h0 = h[(s0 << 6) + lane];
    float h1v = h[(s1 << 6) + lane];
    float h2v = h[(s2 << 6) + lane];
    float h3 = h[(s3 << 6) + lane];
    acc += w0 * h0 + w1 * h1v + w2 * h2v + w3 * h3;
    if (DUAL){
      float a0 = caw[i], a1 = caw[i+1], a2 = caw[i+2], a3 = caw[i+3];
      acc2 += a0 * h0 + a1 * h1v + a2 * h2v + a3 * h3;
    }
  }
  for (; i < e; i++){
    int src = cs[i];
    float hv = h[(src << 6) + lane];
    acc += cw[i] * hv;
    if (DUAL) acc2 += caw[i] * hv;
  }
  float x = acc + bias[lane];
  float al = alpha[0];
  out1[(node << 6) + lane] = (x >= 0.f) ? x : al * x;
  if (DUAL) out2[(node << 6) + lane] = acc2;
}

// ---------------- fused dots (blocks [0,2048)) + negatives (blocks [2048,10240)) ----------------
__global__ __launch_bounds__(256) void dotsneg_k(const float* __restrict__ nv,
    const float* __restrict__ M1, const float* __restrict__ M2, const float* __restrict__ nn,
    const float* __restrict__ Wsv, const float* __restrict__ bs,
    const float* __restrict__ bd1, const float* __restrict__ bd2,
    const int* __restrict__ neg1, const int* __restrict__ neg2,
    float* __restrict__ p1, float* __restrict__ p2, float* __restrict__ score,
    float* __restrict__ n1, float* __restrict__ n2){
  int b = blockIdx.x;
  int wv = threadIdx.x >> 6, t = threadIdx.x & 63;
  if (b < (Nn >> 2)){
    int node = (b << 2) + wv;
    float v = nv[(node << 6) + t];
    float s1 = wave_sum(M1[(node << 6) + t] * v);
    float s2 = wave_sum(M2[(node << 6) + t] * nn[(node << 6) + t]);
    float s3 = wave_sum(v * Wsv[t]);
    if (t == 0){
      p1[node] = s1 + bd1[0];
      p2[node] = s2 + bd2[0];
      score[node] = 1.f / (1.f + __expf(-(s3 + bs[0])));
    }
  } else {
    int gid = ((b - (Nn >> 2)) << 2) + wv;
    int n = gid & (Nn - 1);
    int i1 = neg1[gid], i2 = neg2[gid];
    float d1 = wave_sum(M1[(i1 << 6) + t] * nv[(n << 6) + t]);
    float d2 = wave_sum(M2[(i2 << 6) + t] * nn[(n << 6) + t]);
    if (t == 0){ n1[gid] = d1 + bd1[0]; n2[gid] = d2 + bd2[0]; }
  }
}

// ---------------- subgraph losses (256 thr: 2 threads per lap row) + final atomics ----------------
__global__ __launch_bounds__(256) void subg_k(const float* __restrict__ score,
    const int* __restrict__ aidx, const int* __restrict__ nidx,
    const float* __restrict__ alap, const float* __restrict__ nlap,
    float* __restrict__ out){
  __shared__ float as_[128], ns_[128];
  __shared__ float pya[256], pyn[256];
  __shared__ float red[4];
  int s = blockIdx.x, t = threadIdx.x;
  int r = t >> 1, half = t & 1;
  if (t < 128){
    as_[t] = score[aidx[s * 128 + t]];
    ns_[t] = score[nidx[s * 128 + t]];
  }
  __syncthreads();
  const float* la = alap + (size_t)s * 16384 + r * 128 + half * 64;
  const float* ln = nlap + (size_t)s * 16384 + r * 128 + half * 64;
  float ya = 0.f, yn = 0.f;
  #pragma unroll 4
  for (int j = 0; j < 64; j += 4){
    int jj = half * 64 + j;
    float4 wa = *(const float4*)(la + j);
    ya += wa.x * as_[jj] + wa.y * as_[jj + 1] + wa.z * as_[jj + 2] + wa.w * as_[jj + 3];
    float4 wn = *(const float4*)(ln + j);
    yn += wn.x * ns_[jj] + wn.y * ns_[jj + 1] + wn.z * ns_[jj + 2] + wn.w * ns_[jj + 3];
  }
  pya[t] = ya; pyn[t] = yn;
  __syncthreads();
  int wid = t >> 6, lane = t & 63;
  float av = 0.f, nvv = 0.f, hom = 0.f;
  bool act = (t < 128);
  if (act){
    av = as_[t]; nvv = ns_[t];
    hom = av * (pya[2 * t] + pya[2 * t + 1]) + nvv * (pyn[2 * t] + pyn[2 * t + 1]);
  }
  float w;
  w = wave_sum(act ? av : 0.f); if (lane == 0) red[wid] = w; __syncthreads();
  float sumA = red[0] + red[1] + red[2] + red[3]; __syncthreads();
  w = wave_sum(hom); if (lane == 0) red[wid] = w; __syncthreads();
  float homS = red[0] + red[1] + red[2] + red[3]; __syncthreads();
  w = wave_max(act ? av : -3.0e38f); if (lane == 0) red[wid] = w; __syncthreads();
  float maxA = fmaxf(fmaxf(red[0], red[1]), fmaxf(red[2], red[3])); __syncthreads();
  w = wave_max(act ? nvv : -3.0e38f); if (lane == 0) red[wid] = w; __syncthreads();
  float maxN = fmaxf(fmaxf(red[0], red[1]), fmaxf(red[2], red[3])); __syncthreads();
  float mean = sumA * (1.f / 128.f);
  float below = (act && av < mean) ? av : -3.0e38f;
  w = wave_max(below); if (lane == 0) red[wid] = w; __syncthreads();
  float mb = fmaxf(fmaxf(red[0], red[1]), fmaxf(red[2], red[3]));
  float a_at_avg = (mb < -1.0e37f) ? maxA : mb;
  if (t == 0){
    atomicAdd(out + 0, fmaxf(0.f, 1.f - maxA + maxN) * (1.f / 128.f));
    atomicAdd(out + 1, fmaxf(0.f, 1.f - maxA + a_at_avg) * (1.f / 128.f));
    atomicAdd(out + 2, sumA * (1.f / 128.f));
    atomicAdd(out + 3, homS * (1.f / 256.f));
  }
}

// ---------------- adj_rebuilt = sigmoid(V @ V^T) via split-bf16 MFMA, nontemporal stores ----------------
__global__ __launch_bounds__(256) void adj_mfma_k(const unsigned short* __restrict__ hi,
    const unsigned short* __restrict__ lo, float* __restrict__ C){
  int tid = threadIdx.x;
  int wave = tid >> 6, lane = tid & 63;
  int quad = lane >> 4, m = lane & 15;
  int rowBase = (blockIdx.y << 7) + ((wave >> 1) << 6);
  int colBase = (blockIdx.x << 7) + ((wave & 1) << 6);

  f32x4 acc[4][4];
  #pragma unroll
  for (int i = 0; i < 4; i++)
    #pragma unroll
    for (int j = 0; j < 4; j++) acc[i][j] = (f32x4){0.f, 0.f, 0.f, 0.f};

  const unsigned short* Ah = hi + ((rowBase + m) << 6) + (quad << 3);
  const unsigned short* Al = lo + ((rowBase + m) << 6) + (quad << 3);
  const unsigned short* Bh = hi + ((colBase + m) << 6) + (quad << 3);
  const unsigned short* Bl = lo + ((colBase + m) << 6) + (quad << 3);

  #pragma unroll
  for (int h = 0; h < 2; h++){
    int ko = h << 5;
    short8 ah[4], al[4], bh[4], bl[4];
    #pragma unroll
    for (int i = 0; i < 4; i++){
      ah[i] = *(const short8*)(Ah + (i << 10) + ko);
      al[i] = *(const short8*)(Al + (i << 10) + ko);
      bh[i] = *(const short8*)(Bh + (i << 10) + ko);
      bl[i] = *(const short8*)(Bl + (i << 10) + ko);
    }
    #pragma unroll
    for (int i = 0; i < 4; i++)
      #pragma unroll
      for (int j = 0; j < 4; j++){
        acc[i][j] = __builtin_amdgcn_mfma_f32_16x16x32_bf16(ah[i], bh[j], acc[i][j], 0, 0, 0);
        acc[i][j] = __builtin_amdgcn_mfma_f32_16x16x32_bf16(ah[i], bl[j], acc[i][j], 0, 0, 0);
        acc[i][j] = __builtin_amdgcn_mfma_f32_16x16x32_bf16(al[i], bh[j], acc[i][j], 0, 0, 0);
      }
  }

  #pragma unroll
  for (int i = 0; i < 4; i++){
    #pragma unroll
    for (int r = 0; r < 4; r++){
      size_t row = (size_t)(rowBase + (i << 4) + (quad << 2) + r);
      float* cp = C + row * Nn + colBase + m;
      #pragma unroll
      for (int j = 0; j < 4; j++){
        float x = acc[i][j][r];
        __builtin_nontemporal_store(1.f / (1.f + __expf(-x)), cp + (j << 4));
      }
    }
  }
}

extern "C" void kernel_launch(void* const* d_in, const int* in_sizes, int n_in,
                              void* d_out, int out_size, void* d_ws, size_t ws_size,
                              hipStream_t stream) {
  const float* feat  = (const float*)d_in[0];
  const int*   esrc  = (const int*)d_in[1];
  const int*   edst  = (const int*)d_in[2];
  const float* ewv   = (const float*)d_in[3];
  const float* eawv  = (const float*)d_in[4];
  const int*   neg1  = (const int*)d_in[5];
  const int*   neg2  = (const int*)d_in[6];
  const int*   aidx  = (const int*)d_in[7];
  const int*   nidx  = (const int*)d_in[8];
  const float* alap  = (const float*)d_in[9];
  const float* nlap  = (const float*)d_in[10];
  const float* W1    = (const float*)d_in[11];
  const float* b1    = (const float*)d_in[12];
  const float* W2    = (const float*)d_in[13];
  const float* b2    = (const float*)d_in[14];
  const float* Wq    = (const float*)d_in[15];
  const float* bq    = (const float*)d_in[16];
  const float* Wsv   = (const float*)d_in[17];
  const float* bs    = (const float*)d_in[18];
  const float* B1    = (const float*)d_in[19];
  const float* bd1   = (const float*)d_in[20];
  const float* B2    = (const float*)d_in[21];
  const float* bd2   = (const float*)d_in[22];
  const float* a1    = (const float*)d_in[23];
  const float* a2    = (const float*)d_in[24];
  const float* aq    = (const float*)d_in[25];

  float* ws  = (float*)d_ws;
  float* h1  = ws + OFF_H1;
  float* M1  = ws + OFF_M1;
  float* v1  = ws + OFF_V1;
  float* nn  = ws + OFF_NN;
  float* h2  = ws + OFF_H2;
  float* v2  = ws + OFF_V2;
  float* nv  = ws + OFF_NV;
  float* M2  = ws + OFF_M2;
  float* sc  = ws + OFF_SC;
  int*   cnt = (int*)(ws + OFF_CNT);
  int*   cur = (int*)(ws + OFF_CUR);
  int*   rs  = (int*)(ws + OFF_RS);
  int*   cs  = (int*)(ws + OFF_ESRC);
  float* cw  = ws + OFF_EW;
  float* caw = ws + OFF_EAW;
  unsigned short* nvh = (unsigned short*)(ws + OFF_NVH);
  unsigned short* nvl = (unsigned short*)(ws + OFF_NVL);
  float* Wt  = ws + OFF_WT;
  float* Wt1 = Wt;           float* WtB1 = Wt + 4096;
  float* Wt2 = Wt + 8192;    float* Wtq  = Wt + 12288;
  float* WtB2 = Wt + 16384;

  float* out = (float*)d_out;
  float* adj = out + 4;
  float* p1  = adj + (size_t)Nn * Nn;
  float* n1o = p1 + Nn;
  float* p2  = n1o + NEGk * Nn;
  float* n2o = p2 + Nn;

  // prep (wtrans + zero) + CSR build
  prep_k<<<145, 256, 0, stream>>>(W1, B1, W2, Wq, B2, Wt, cnt, cur, out);
  hist_k<<<Ee / 256, 256, 0, stream>>>(edst, cnt);
  scan_k<<<1, 256, 0, stream>>>(cnt, rs);
  scatter_k<<<Ee / 256, 256, 0, stream>>>(edst, esrc, ewv, eawv, rs, cur, cs, cw, caw);

  // GCN pipeline
  fc2_k<true ><<<Nn / 32, 256, 0, stream>>>(feat, Wt1, WtB1, h1, M1);
  agg_k<true ><<<Nn / 4, 256, 0, stream>>>(h1, rs, cs, cw, caw, b1, a1, v1, nn);
  fc2_k<false><<<Nn / 32, 256, 0, stream>>>(v1, Wt2, nullptr, h2, nullptr);
  agg_k<false><<<Nn / 4, 256, 0, stream>>>(h2, rs, cs, cw, caw, b2, a2, v2, nullptr);
  fcq_k<<<Nn / 32, 256, 0, stream>>>(v2, Wtq, WtB2, bq, aq, nv, M2, nvh, nvl);

  // discriminators + scores (fused dots+neg)
  dotsneg_k<<<(Nn / 4) + (NEGk * Nn / 4), 256, 0, stream>>>(nv, M1, M2, nn, Wsv, bs, bd1, bd2,
                                                            neg1, neg2, p1, p2, sc, n1o, n2o);

  // subgraph losses (finals via atomics into out[0:4], zeroed by prep_k)
  subg_k<<<128, 256, 0, stream>>>(sc, aidx, nidx, alap, nlap, out);

  // big one: split-bf16 MFMA, write-bandwidth-bound, nontemporal stores
  adj_mfma_k<<<dim3(Nn / 128, Nn / 128), 256, 0, stream>>>(nvh, nvl, adj);
}

// Round 5
// 482.361 us; speedup vs baseline: 1.1424x; 1.1424x over previous
//
#include <hip/hip_runtime.h>

#define Nn 8192
#define Ee 262144
#define NEGk 4

// ---- workspace float offsets ----
#define OFF_H1   0u
#define OFF_M1   524288u
#define OFF_V1   1048576u
#define OFF_NN   1572864u
#define OFF_H2   2097152u
#define OFF_V2   2621440u
#define OFF_NV   3145728u
#define OFF_M2   3670016u
#define OFF_SC   4194304u
#define OFF_CNT  4203008u
#define OFF_CUR  4211200u
#define OFF_RS   4219392u
#define OFF_ESRC 4227600u
#define OFF_EW   4489744u
#define OFF_EAW  4751888u
#define OFF_NVH  5014032u   // 8192*64 ushort = 262144 floats
#define OFF_NVL  5276176u
#define OFF_WT   5538320u   // 5 * 4096 floats of transposed weights

using short8 = __attribute__((ext_vector_type(8))) short;
using f32x4  = __attribute__((ext_vector_type(4))) float;

__device__ inline float wave_sum(float v){
  #pragma unroll
  for (int o = 32; o > 0; o >>= 1) v += __shfl_down(v, o, 64);
  return v;
}
__device__ inline float wave_max(float v){
  #pragma unroll
  for (int o = 32; o > 0; o >>= 1) v = fmaxf(v, __shfl_down(v, o, 64));
  return v;
}
__device__ inline unsigned short f2bf(float x){
  unsigned u = __float_as_uint(x);
  unsigned r = (u + 0x7FFFu + ((u >> 16) & 1u)) >> 16;
  return (unsigned short)r;
}
__device__ inline float bf2f(unsigned short h){ return __uint_as_float(((unsigned)h) << 16); }

// ---------------- prep: weight transposes + zero cnt/cur + zero out[0:4] ----------------
__global__ __launch_bounds__(256) void prep_k(const float* __restrict__ W1, const float* __restrict__ B1,
    const float* __restrict__ W2, const float* __restrict__ Wq, const float* __restrict__ B2,
    float* __restrict__ Wt, int* __restrict__ cnt, int* __restrict__ cur, float* __restrict__ out4){
  int idx = blockIdx.x * 256 + threadIdx.x;
  if (idx < 20480){
    int m = idx >> 12, rc = idx & 4095;
    int k = rc >> 6, c = rc & 63;
    const float* src = (m == 0) ? W1 : (m == 1) ? B1 : (m == 2) ? W2 : (m == 3) ? Wq : B2;
    Wt[m * 4096 + c * 64 + k] = src[k * 64 + c];
  } else if (idx < 28672){
    cnt[idx - 20480] = 0;
  } else if (idx < 36864){
    cur[idx - 28672] = 0;
  } else if (idx < 36868){
    out4[idx - 36864] = 0.f;
  }
}

// ---------------- CSR build ----------------
__global__ __launch_bounds__(256) void hist_k(const int* __restrict__ dst, int* __restrict__ cnt){
  int e = blockIdx.x * 256 + threadIdx.x;
  atomicAdd(&cnt[dst[e]], 1);
}

__global__ __launch_bounds__(256) void scan_k(const int* __restrict__ cnt, int* __restrict__ rs){
  __shared__ int part[256];
  int tid = threadIdx.x;
  int base = tid * 32;
  int local[32]; int s = 0;
  #pragma unroll
  for (int i = 0; i < 32; i++){ local[i] = s; s += cnt[base + i]; }
  part[tid] = s; __syncthreads();
  for (int off = 1; off < 256; off <<= 1){
    int v = (tid >= off) ? part[tid - off] : 0;
    __syncthreads();
    part[tid] += v;
    __syncthreads();
  }
  int ex = part[tid] - s;
  #pragma unroll
  for (int i = 0; i < 32; i++) rs[base + i] = ex + local[i];
  if (tid == 255) rs[Nn] = part[255];
}

__global__ __launch_bounds__(256) void scatter_k(const int* __restrict__ dst, const int* __restrict__ src,
    const float* __restrict__ ew, const float* __restrict__ aw,
    const int* __restrict__ rs, int* __restrict__ cur,
    int* __restrict__ cs, float* __restrict__ cw, float* __restrict__ caw){
  int e = blockIdx.x * 256 + threadIdx.x;
  int d = dst[e];
  int pos = atomicAdd(&cur[d], 1);
  int j = rs[d] + pos;
  cs[j] = src[e]; cw[j] = ew[e]; caw[j] = aw[e];
}

// ---------------- FC: Y = X(Nx64) @ W(64x64), W pre-transposed; optional dual ----------------
template<bool DUAL>
__global__ __launch_bounds__(256) void fc2_k(const float* __restrict__ X,
    const float* __restrict__ WtA, const float* __restrict__ WtB,
    float* __restrict__ Ya, float* __restrict__ Yb){
  __shared__ float As[32 * 68];
  int tid = threadIdx.x;
  int r0 = blockIdx.x * 32;
  for (int i = tid; i < 512; i += 256){
    int r = i >> 4, kq = (i & 15) << 2;
    *(float4*)(As + r * 68 + kq) = *(const float4*)(X + (r0 + r) * 64 + kq);
  }
  __syncthreads();
  int tx = tid & 63, wv = tid >> 6;
  float acca[8], accb[8];
  #pragma unroll
  for (int r = 0; r < 8; r++){ acca[r] = 0.f; accb[r] = 0.f; }
  const float* wpa = WtA + tx * 64;
  const float* wpb = DUAL ? (WtB + tx * 64) : WtA;
  #pragma unroll 4
  for (int kq = 0; kq < 64; kq += 4){
    float4 w = *(const float4*)(wpa + kq);
    float4 w2 = *(const float4*)(wpb + kq);
    #pragma unroll
    for (int r = 0; r < 8; r++){
      float4 a = *(const float4*)(As + (wv * 8 + r) * 68 + kq);
      acca[r] += a.x * w.x + a.y * w.y + a.z * w.z + a.w * w.w;
      if (DUAL) accb[r] += a.x * w2.x + a.y * w2.y + a.z * w2.z + a.w * w2.w;
    }
  }
  #pragma unroll
  for (int r = 0; r < 8; r++){
    int row = r0 + wv * 8 + r;
    Ya[row * 64 + tx] = acca[r];
    if (DUAL) Yb[row * 64 + tx] = accb[r];
  }
}

// ---------------- fused: nv = prelu(v2@Wq + bq); bf16-split(nv); M2 = nv@B2 ----------------
__global__ __launch_bounds__(256) void fcq_k(const float* __restrict__ X,
    const float* __restrict__ Wtq, const float* __restrict__ WtB2,
    const float* __restrict__ bias, const float* __restrict__ alpha,
    float* __restrict__ nv, float* __restrict__ M2,
    unsigned short* __restrict__ hi, unsigned short* __restrict__ lo){
  __shared__ float As[32 * 68];
  __shared__ float Ns[32 * 68];
  int tid = threadIdx.x;
  int r0 = blockIdx.x * 32;
  for (int i = tid; i < 512; i += 256){
    int r = i >> 4, kq = (i & 15) << 2;
    *(float4*)(As + r * 68 + kq) = *(const float4*)(X + (r0 + r) * 64 + kq);
  }
  __syncthreads();
  int tx = tid & 63, wv = tid >> 6;
  float acc[8];
  #pragma unroll
  for (int r = 0; r < 8; r++) acc[r] = 0.f;
  const float* wp = Wtq + tx * 64;
  #pragma unroll 4
  for (int kq = 0; kq < 64; kq += 4){
    float4 w = *(const float4*)(wp + kq);
    #pragma unroll
    for (int r = 0; r < 8; r++){
      float4 a = *(const float4*)(As + (wv * 8 + r) * 68 + kq);
      acc[r] += a.x * w.x + a.y * w.y + a.z * w.z + a.w * w.w;
    }
  }
  float al = alpha[0];
  float bi = bias[tx];
  #pragma unroll
  for (int r = 0; r < 8; r++){
    int row = r0 + wv * 8 + r;
    float x = acc[r] + bi;
    x = (x >= 0.f) ? x : al * x;
    nv[row * 64 + tx] = x;
    unsigned short h = f2bf(x);
    hi[row * 64 + tx] = h;
    lo[row * 64 + tx] = f2bf(x - bf2f(h));
    Ns[(wv * 8 + r) * 68 + tx] = x;
  }
  __syncthreads();
  float acc2[8];
  #pragma unroll
  for (int r = 0; r < 8; r++) acc2[r] = 0.f;
  const float* wp2 = WtB2 + tx * 64;
  #pragma unroll 4
  for (int kq = 0; kq < 64; kq += 4){
    float4 w = *(const float4*)(wp2 + kq);
    #pragma unroll
    for (int r = 0; r < 8; r++){
      float4 a = *(const float4*)(Ns + (wv * 8 + r) * 68 + kq);
      acc2[r] += a.x * w.x + a.y * w.y + a.z * w.z + a.w * w.w;
    }
  }
  #pragma unroll
  for (int r = 0; r < 8; r++){
    int row = r0 + wv * 8 + r;
    M2[row * 64 + tx] = acc2[r];
  }
}

// ---------------- SpMM aggregation (CSR), 4x unrolled ----------------
template<bool DUAL>
__global__ __launch_bounds__(256) void agg_k(const float* __restrict__ h,
    const int* __restrict__ rs, const int* __restrict__ cs,
    const float* __restrict__ cw, const float* __restrict__ caw,
    const float* __restrict__ bias, const float* __restrict__ alpha,
    float* __restrict__ out1, float* __restrict__ out2){
  int node = (blockIdx.x << 2) + (threadIdx.x >> 6);
  int lane = threadIdx.x & 63;
  int s = rs[node], e = rs[node + 1];
  float acc = 0.f, acc2 = 0.f;
  int i = s;
  for (; i + 4 <= e; i += 4){
    int s0 = cs[i], s1 = cs[i+1], s2 = cs[i+2], s3 = cs[i+3];
    float w0 = cw[i], w1 = cw[i+1], w2 = cw[i+2], w3 = cw[i+3];
    float h0 = h[(s0 << 6) + lane];
    float h1v = h[(s1 << 6) + lane];
    float h2v = h[(s2 << 6) + lane];
    float h3 = h[(s3 << 6) + lane];
    acc += w0 * h0 + w1 * h1v + w2 * h2v + w3 * h3;
    if (DUAL){
      float a0 = caw[i], a1 = caw[i+1], a2 = caw[i+2], a3 = caw[i+3];
      acc2 += a0 * h0 + a1 * h1v + a2 * h2v + a3 * h3;
    }
  }
  for (; i < e; i++){
    int src = cs[i];
    float hv = h[(src << 6) + lane];
    acc += cw[i] * hv;
    if (DUAL) acc2 += caw[i] * hv;
  }
  float x = acc + bias[lane];
  float al = alpha[0];
  out1[(node << 6) + lane] = (x >= 0.f) ? x : al * x;
  if (DUAL) out2[(node << 6) + lane] = acc2;
}

// ---------------- fused dots (blocks [0,2048)) + negatives (blocks [2048,10240)) ----------------
__global__ __launch_bounds__(256) void dotsneg_k(const float* __restrict__ nv,
    const float* __restrict__ M1, const float* __restrict__ M2, const float* __restrict__ nn,
    const float* __restrict__ Wsv, const float* __restrict__ bs,
    const float* __restrict__ bd1, const float* __restrict__ bd2,
    const int* __restrict__ neg1, const int* __restrict__ neg2,
    float* __restrict__ p1, float* __restrict__ p2, float* __restrict__ score,
    float* __restrict__ n1, float* __restrict__ n2){
  int b = blockIdx.x;
  int wv = threadIdx.x >> 6, t = threadIdx.x & 63;
  if (b < (Nn >> 2)){
    int node = (b << 2) + wv;
    float v = nv[(node << 6) + t];
    float s1 = wave_sum(M1[(node << 6) + t] * v);
    float s2 = wave_sum(M2[(node << 6) + t] * nn[(node << 6) + t]);
    float s3 = wave_sum(v * Wsv[t]);
    if (t == 0){
      p1[node] = s1 + bd1[0];
      p2[node] = s2 + bd2[0];
      score[node] = 1.f / (1.f + __expf(-(s3 + bs[0])));
    }
  } else {
    int gid = ((b - (Nn >> 2)) << 2) + wv;
    int n = gid & (Nn - 1);
    int i1 = neg1[gid], i2 = neg2[gid];
    float d1 = wave_sum(M1[(i1 << 6) + t] * nv[(n << 6) + t]);
    float d2 = wave_sum(M2[(i2 << 6) + t] * nn[(n << 6) + t]);
    if (t == 0){ n1[gid] = d1 + bd1[0]; n2[gid] = d2 + bd2[0]; }
  }
}

// ---------------- subgraph losses (256 thr: 2 threads per lap row) + final atomics ----------------
__global__ __launch_bounds__(256) void subg_k(const float* __restrict__ score,
    const int* __restrict__ aidx, const int* __restrict__ nidx,
    const float* __restrict__ alap, const float* __restrict__ nlap,
    float* __restrict__ out){
  __shared__ float as_[128], ns_[128];
  __shared__ float pya[256], pyn[256];
  __shared__ float red[4];
  int s = blockIdx.x, t = threadIdx.x;
  int r = t >> 1, half = t & 1;
  if (t < 128){
    as_[t] = score[aidx[s * 128 + t]];
    ns_[t] = score[nidx[s * 128 + t]];
  }
  __syncthreads();
  const float* la = alap + (size_t)s * 16384 + r * 128 + half * 64;
  const float* ln = nlap + (size_t)s * 16384 + r * 128 + half * 64;
  float ya = 0.f, yn = 0.f;
  #pragma unroll 4
  for (int j = 0; j < 64; j += 4){
    int jj = half * 64 + j;
    float4 wa = *(const float4*)(la + j);
    ya += wa.x * as_[jj] + wa.y * as_[jj + 1] + wa.z * as_[jj + 2] + wa.w * as_[jj + 3];
    float4 wn = *(const float4*)(ln + j);
    yn += wn.x * ns_[jj] + wn.y * ns_[jj + 1] + wn.z * ns_[jj + 2] + wn.w * ns_[jj + 3];
  }
  pya[t] = ya; pyn[t] = yn;
  __syncthreads();
  int wid = t >> 6, lane = t & 63;
  float av = 0.f, nvv = 0.f, hom = 0.f;
  bool act = (t < 128);
  if (act){
    av = as_[t]; nvv = ns_[t];
    hom = av * (pya[2 * t] + pya[2 * t + 1]) + nvv * (pyn[2 * t] + pyn[2 * t + 1]);
  }
  float w;
  w = wave_sum(act ? av : 0.f); if (lane == 0) red[wid] = w; __syncthreads();
  float sumA = red[0] + red[1] + red[2] + red[3]; __syncthreads();
  w = wave_sum(hom); if (lane == 0) red[wid] = w; __syncthreads();
  float homS = red[0] + red[1] + red[2] + red[3]; __syncthreads();
  w = wave_max(act ? av : -3.0e38f); if (lane == 0) red[wid] = w; __syncthreads();
  float maxA = fmaxf(fmaxf(red[0], red[1]), fmaxf(red[2], red[3])); __syncthreads();
  w = wave_max(act ? nvv : -3.0e38f); if (lane == 0) red[wid] = w; __syncthreads();
  float maxN = fmaxf(fmaxf(red[0], red[1]), fmaxf(red[2], red[3])); __syncthreads();
  float mean = sumA * (1.f / 128.f);
  float below = (act && av < mean) ? av : -3.0e38f;
  w = wave_max(below); if (lane == 0) red[wid] = w; __syncthreads();
  float mb = fmaxf(fmaxf(red[0], red[1]), fmaxf(red[2], red[3]));
  float a_at_avg = (mb < -1.0e37f) ? maxA : mb;
  if (t == 0){
    atomicAdd(out + 0, fmaxf(0.f, 1.f - maxA + maxN) * (1.f / 128.f));
    atomicAdd(out + 1, fmaxf(0.f, 1.f - maxA + a_at_avg) * (1.f / 128.f));
    atomicAdd(out + 2, sumA * (1.f / 128.f));
    atomicAdd(out + 3, homS * (1.f / 256.f));
  }
}

// ---------------- adj_rebuilt = sigmoid(V @ V^T) via split-bf16 MFMA ----------------
// C-layout scalar stores were 64B partial-line nt writes (1.6x HBM amplification, R3).
// Now: stage each wave's 16x64 strip via LDS (stride 68 -> 2-way conflicts = free,
// double-buffered over strips), read back f32x4, sigmoid, nt 16B full-line stores.
__global__ __launch_bounds__(256) void adj_mfma_k(const unsigned short* __restrict__ hi,
    const unsigned short* __restrict__ lo, float* __restrict__ C){
  __shared__ __align__(16) float st[4][2][16 * 68];
  int tid = threadIdx.x;
  int wave = tid >> 6, lane = tid & 63;
  int quad = lane >> 4, m = lane & 15;
  int rowBase = (blockIdx.y << 7) + ((wave >> 1) << 6);
  int colBase = (blockIdx.x << 7) + ((wave & 1) << 6);

  f32x4 acc[4][4];
  #pragma unroll
  for (int i = 0; i < 4; i++)
    #pragma unroll
    for (int j = 0; j < 4; j++) acc[i][j] = (f32x4){0.f, 0.f, 0.f, 0.f};

  const unsigned short* Ah = hi + ((rowBase + m) << 6) + (quad << 3);
  const unsigned short* Al = lo + ((rowBase + m) << 6) + (quad << 3);
  const unsigned short* Bh = hi + ((colBase + m) << 6) + (quad << 3);
  const unsigned short* Bl = lo + ((colBase + m) << 6) + (quad << 3);

  #pragma unroll
  for (int h = 0; h < 2; h++){
    int ko = h << 5;
    short8 ah[4], al[4], bh[4], bl[4];
    #pragma unroll
    for (int i = 0; i < 4; i++){
      ah[i] = *(const short8*)(Ah + (i << 10) + ko);
      al[i] = *(const short8*)(Al + (i << 10) + ko);
      bh[i] = *(const short8*)(Bh + (i << 10) + ko);
      bl[i] = *(const short8*)(Bl + (i << 10) + ko);
    }
    #pragma unroll
    for (int i = 0; i < 4; i++)
      #pragma unroll
      for (int j = 0; j < 4; j++){
        acc[i][j] = __builtin_amdgcn_mfma_f32_16x16x32_bf16(ah[i], bh[j], acc[i][j], 0, 0, 0);
        acc[i][j] = __builtin_amdgcn_mfma_f32_16x16x32_bf16(ah[i], bl[j], acc[i][j], 0, 0, 0);
        acc[i][j] = __builtin_amdgcn_mfma_f32_16x16x32_bf16(al[i], bh[j], acc[i][j], 0, 0, 0);
      }
  }

  int rr = lane >> 4;        // output sub-row group 0..3
  int c4 = lane & 15;        // f32x4 column index 0..15
  #pragma unroll
  for (int i = 0; i < 4; i++){
    float* S = st[wave][i & 1];
    // write MFMA-layout strip (16 rows x 64 cols) to LDS
    #pragma unroll
    for (int j = 0; j < 4; j++)
      #pragma unroll
      for (int r = 0; r < 4; r++)
        S[((quad << 2) + r) * 68 + (j << 4) + m] = acc[i][j][r];
    __syncthreads();
    // read back row-major, sigmoid, full-line nt stores
    #pragma unroll
    for (int t = 0; t < 4; t++){
      int row_l = rr + (t << 2);
      f32x4 v = *(const f32x4*)(S + row_l * 68 + (c4 << 2));
      f32x4 o;
      o[0] = 1.f / (1.f + __expf(-v[0]));
      o[1] = 1.f / (1.f + __expf(-v[1]));
      o[2] = 1.f / (1.f + __expf(-v[2]));
      o[3] = 1.f / (1.f + __expf(-v[3]));
      size_t row = (size_t)(rowBase + (i << 4) + row_l);
      __builtin_nontemporal_store(o, (f32x4*)(C + row * Nn + colBase + (c4 << 2)));
    }
  }
}

extern "C" void kernel_launch(void* const* d_in, const int* in_sizes, int n_in,
                              void* d_out, int out_size, void* d_ws, size_t ws_size,
                              hipStream_t stream) {
  const float* feat  = (const float*)d_in[0];
  const int*   esrc  = (const int*)d_in[1];
  const int*   edst  = (const int*)d_in[2];
  const float* ewv   = (const float*)d_in[3];
  const float* eawv  = (const float*)d_in[4];
  const int*   neg1  = (const int*)d_in[5];
  const int*   neg2  = (const int*)d_in[6];
  const int*   aidx  = (const int*)d_in[7];
  const int*   nidx  = (const int*)d_in[8];
  const float* alap  = (const float*)d_in[9];
  const float* nlap  = (const float*)d_in[10];
  const float* W1    = (const float*)d_in[11];
  const float* b1    = (const float*)d_in[12];
  const float* W2    = (const float*)d_in[13];
  const float* b2    = (const float*)d_in[14];
  const float* Wq    = (const float*)d_in[15];
  const float* bq    = (const float*)d_in[16];
  const float* Wsv   = (const float*)d_in[17];
  const float* bs    = (const float*)d_in[18];
  const float* B1    = (const float*)d_in[19];
  const float* bd1   = (const float*)d_in[20];
  const float* B2    = (const float*)d_in[21];
  const float* bd2   = (const float*)d_in[22];
  const float* a1    = (const float*)d_in[23];
  const float* a2    = (const float*)d_in[24];
  const float* aq    = (const float*)d_in[25];

  float* ws  = (float*)d_ws;
  float* h1  = ws + OFF_H1;
  float* M1  = ws + OFF_M1;
  float* v1  = ws + OFF_V1;
  float* nn  = ws + OFF_NN;
  float* h2  = ws + OFF_H2;
  float* v2  = ws + OFF_V2;
  float* nv  = ws + OFF_NV;
  float* M2  = ws + OFF_M2;
  float* sc  = ws + OFF_SC;
  int*   cnt = (int*)(ws + OFF_CNT);
  int*   cur = (int*)(ws + OFF_CUR);
  int*   rs  = (int*)(ws + OFF_RS);
  int*   cs  = (int*)(ws + OFF_ESRC);
  float* cw  = ws + OFF_EW;
  float* caw = ws + OFF_EAW;
  unsigned short* nvh = (unsigned short*)(ws + OFF_NVH);
  unsigned short* nvl = (unsigned short*)(ws + OFF_NVL);
  float* Wt  = ws + OFF_WT;
  float* Wt1 = Wt;           float* WtB1 = Wt + 4096;
  float* Wt2 = Wt + 8192;    float* Wtq  = Wt + 12288;
  float* WtB2 = Wt + 16384;

  float* out = (float*)d_out;
  float* adj = out + 4;
  float* p1  = adj + (size_t)Nn * Nn;
  float* n1o = p1 + Nn;
  float* p2  = n1o + NEGk * Nn;
  float* n2o = p2 + Nn;

  // prep (wtrans + zero) + CSR build
  prep_k<<<145, 256, 0, stream>>>(W1, B1, W2, Wq, B2, Wt, cnt, cur, out);
  hist_k<<<Ee / 256, 256, 0, stream>>>(edst, cnt);
  scan_k<<<1, 256, 0, stream>>>(cnt, rs);
  scatter_k<<<Ee / 256, 256, 0, stream>>>(edst, esrc, ewv, eawv, rs, cur, cs, cw, caw);

  // GCN pipeline
  fc2_k<true ><<<Nn / 32, 256, 0, stream>>>(feat, Wt1, WtB1, h1, M1);
  agg_k<true ><<<Nn / 4, 256, 0, stream>>>(h1, rs, cs, cw, caw, b1, a1, v1, nn);
  fc2_k<false><<<Nn / 32, 256, 0, stream>>>(v1, Wt2, nullptr, h2, nullptr);
  agg_k<false><<<Nn / 4, 256, 0, stream>>>(h2, rs, cs, cw, caw, b2, a2, v2, nullptr);
  fcq_k<<<Nn / 32, 256, 0, stream>>>(v2, Wtq, WtB2, bq, aq, nv, M2, nvh, nvl);

  // discriminators + scores (fused dots+neg)
  dotsneg_k<<<(Nn / 4) + (NEGk * Nn / 4), 256, 0, stream>>>(nv, M1, M2, nn, Wsv, bs, bd1, bd2,
                                                            neg1, neg2, p1, p2, sc, n1o, n2o);

  // subgraph losses (finals via atomics into out[0:4], zeroed by prep_k)
  subg_k<<<128, 256, 0, stream>>>(sc, aidx, nidx, alap, nlap, out);

  // big one: split-bf16 MFMA, write-bandwidth-bound, full-line nt stores via LDS staging
  adj_mfma_k<<<dim3(Nn / 128, Nn / 128), 256, 0, stream>>>(nvh, nvl, adj);
}